// Round 1
// baseline (318.782 us; speedup 1.0000x reference)
//
#include <hip/hip_runtime.h>

// ---- problem constants ----
static constexpr int kR    = 896;
static constexpr int kLMAX = 510;
static constexpr int kWMAX = 509;
static constexpr int kHID  = 32;
static constexpr int kENC  = 10;
static constexpr int kGH   = 64;
static constexpr int kNCLS = 10;
static constexpr int kB    = 8;
static constexpr int kEPS  = 7168;
static constexpr int kN    = kB * kR;     // 7168 nodes
static constexpr int kE    = kB * kEPS;   // 57344 edges
static constexpr int kPAD  = 3 * 256 * 256; // 196608

// ---- workspace layout (floats) ----
static constexpr size_t OFF_EMB  = 0;
static constexpr size_t OFF_DEG  = OFF_EMB + (size_t)kN * kENC;   // 71680
static constexpr size_t OFF_DINV = OFF_DEG + kN;
static constexpr size_t OFF_NORM = OFF_DINV + kN;
static constexpr size_t OFF_XW   = OFF_NORM + kE;                 // xw1, reused as xw2
static constexpr size_t OFF_H1   = OFF_XW + (size_t)kN * kGH;
static constexpr size_t OFF_H2   = OFF_H1 + (size_t)kN * kGH;

// =====================================================================
// Kernel 1: fused conv + decoder contraction.
// grid = 1792 blocks: (r, half). block = 320 threads = 5 waves.
// Each wave owns 2 output channels o (5*2 = 10 = ENC).
// LDS: vals[2][8][257] (gathered x), htile[8][64][12] (pad->48B stride for
// conflict-free float4 reads), Wconv/bconv staging.  ~42 KB -> 3 blocks/CU.
// =====================================================================
__global__ __launch_bounds__(320, 2)
void k_conv_emb(const float* __restrict__ x, const int* __restrict__ idx,
                const float* __restrict__ Wconv, const float* __restrict__ bconv,
                const float* __restrict__ Wdec, float* __restrict__ emb)
{
    const int r    = blockIdx.x >> 1;
    const int half = blockIdx.x & 1;
    const int l0   = half ? 256 : 0;
    const int lcnt = half ? (kLMAX - 256) : 257;   // 254 : 257
    const int w0   = half ? 256 : 0;
    const int wtot = half ? (kWMAX - 256) : 256;   // 253 : 256

    __shared__ float vals[2][kB][257];
    __shared__ float htile[8][64][12];   // [c-sub][w-lane][b(+pad)]
    __shared__ float wconv_s[kHID * 4];
    __shared__ float bconv_s[kHID];

    const int tid = threadIdx.x;

    for (int i = tid; i < kHID * 4; i += 320) wconv_s[i] = Wconv[r * kHID * 4 + i];
    if (tid < kHID) bconv_s[tid] = bconv[r * kHID + tid];

    // gather x values via idx (idx==kPAD -> 0)
    for (int hh = 0; hh < 2; ++hh) {
        for (int li = tid; li < lcnt; li += 320) {
            int j = idx[(r * 2 + hh) * kLMAX + l0 + li];
            bool ok = (unsigned)j < (unsigned)kPAD;
            #pragma unroll
            for (int b = 0; b < kB; ++b) {
                vals[hh][b][li] = ok ? x[(size_t)b * kPAD + j] : 0.0f;
            }
        }
    }

    float acc0[8], acc1[8];
    #pragma unroll
    for (int b = 0; b < 8; ++b) { acc0[b] = 0.0f; acc1[b] = 0.0f; }

    const int wave = tid >> 6;
    const int lane = tid & 63;
    const int o0 = wave * 2, o1 = o0 + 1;
    const float* WdR = Wdec + (size_t)r * kENC * kHID * kWMAX;

    for (int ck = 0; ck < 4; ++ck) {
        const int wb   = w0 + ck * 64;
        const int wcnt = min(64, w0 + wtot - wb);
        for (int ct = 0; ct < 4; ++ct) {
            const int c0 = ct * 8;
            __syncthreads();   // previous phase's reads done before overwrite
            // ---- compute h tile: thread -> (w-lane, b), loop 8 channels ----
            for (int i = tid; i < 512; i += 320) {
                const int wl = i >> 3, b = i & 7;
                float v00 = 0, v01 = 0, v10 = 0, v11 = 0;
                if (wl < wcnt) {
                    const int base = wb - l0 + wl;
                    v00 = vals[0][b][base]; v01 = vals[0][b][base + 1];
                    v10 = vals[1][b][base]; v11 = vals[1][b][base + 1];
                }
                #pragma unroll
                for (int cc = 0; cc < 8; ++cc) {
                    const float* wc = &wconv_s[(c0 + cc) * 4];
                    float h = fmaf(v00, wc[0], fmaf(v01, wc[1],
                              fmaf(v10, wc[2], fmaf(v11, wc[3], bconv_s[c0 + cc]))));
                    h = (wl < wcnt) ? fmaxf(h, 0.0f) : 0.0f;
                    htile[cc][wl][b] = h;
                }
            }
            __syncthreads();
            // ---- contract with Wdec: lane -> w, wave -> (o0,o1) ----
            const bool ld = (lane < wcnt);
            const int wg = wb + lane;
            #pragma unroll
            for (int cc = 0; cc < 8; ++cc) {
                const int c = c0 + cc;
                const float4* hp = (const float4*)&htile[cc][lane][0];
                float4 ha = hp[0], hb = hp[1];
                float hv[8] = {ha.x, ha.y, ha.z, ha.w, hb.x, hb.y, hb.z, hb.w};
                float wd0 = ld ? WdR[(size_t)(o0 * kHID + c) * kWMAX + wg] : 0.0f;
                float wd1 = ld ? WdR[(size_t)(o1 * kHID + c) * kWMAX + wg] : 0.0f;
                #pragma unroll
                for (int b = 0; b < 8; ++b) {
                    acc0[b] = fmaf(wd0, hv[b], acc0[b]);
                    acc1[b] = fmaf(wd1, hv[b], acc1[b]);
                }
            }
        }
    }

    // ---- wave-reduce + atomic accumulate into emb ----
    #pragma unroll
    for (int b = 0; b < 8; ++b) {
        float s0 = acc0[b], s1 = acc1[b];
        #pragma unroll
        for (int sft = 32; sft > 0; sft >>= 1) {
            s0 += __shfl_xor(s0, sft);
            s1 += __shfl_xor(s1, sft);
        }
        if (lane == 0) {
            atomicAdd(&emb[(size_t)(b * kR + r) * kENC + o0], s0);
            atomicAdd(&emb[(size_t)(b * kR + r) * kENC + o1], s1);
        }
    }
}

// =====================================================================
// GCN kernels
// =====================================================================
__device__ __forceinline__ float sigmoidf_(float v) { return 1.0f / (1.0f + expf(-v)); }

__global__ void k_deg(const int* __restrict__ ei, const float* __restrict__ edge_w,
                      float* __restrict__ deg)
{
    int e = blockIdx.x * 256 + threadIdx.x;
    if (e >= kE) return;
    int t = ei[kE + e];
    atomicAdd(&deg[t], sigmoidf_(edge_w[e % kEPS]));
}

__global__ void k_dinv(const float* __restrict__ deg, float* __restrict__ dinv)
{
    int i = blockIdx.x * 256 + threadIdx.x;
    if (i < kN) dinv[i] = rsqrtf(deg[i] + 1.0f);   // +1 = self loop; always > 0
}

__global__ void k_norm(const int* __restrict__ ei, const float* __restrict__ edge_w,
                       const float* __restrict__ dinv, float* __restrict__ norm)
{
    int e = blockIdx.x * 256 + threadIdx.x;
    if (e >= kE) return;
    norm[e] = dinv[ei[e]] * sigmoidf_(edge_w[e % kEPS]) * dinv[ei[kE + e]];
}

// xw1 = (emb + bdec) @ Wg1 ; h1 init = bg1 + dinv^2 * xw1
__global__ void k_xw1(const float* __restrict__ emb, const float* __restrict__ bdec,
                      const float* __restrict__ Wg1, const float* __restrict__ bg1,
                      const float* __restrict__ dinv,
                      float* __restrict__ xw1, float* __restrict__ h1)
{
    int t = blockIdx.x * 256 + threadIdx.x;
    int i = t >> 6, f = t & 63;
    int r = i % kR;
    float s = 0.0f;
    #pragma unroll
    for (int o = 0; o < kENC; ++o)
        s = fmaf(emb[i * kENC + o] + bdec[r * kENC + o], Wg1[o * kGH + f], s);
    xw1[t] = s;
    float di = dinv[i];
    h1[t] = bg1[f] + di * di * s;
}

__global__ void k_scatter(const int* __restrict__ ei, const float* __restrict__ norm,
                          const float* __restrict__ xw, float* __restrict__ h)
{
    int t = blockIdx.x * 256 + threadIdx.x;
    int e = t >> 6, f = t & 63;
    float nm = norm[e];
    atomicAdd(&h[(size_t)ei[kE + e] * kGH + f], nm * xw[(size_t)ei[e] * kGH + f]);
}

// xw2 = relu(h1) @ Wg2 ; h2 init = bg2 + dinv^2 * xw2
__global__ void k_xw2(const float* __restrict__ h1, const float* __restrict__ Wg2,
                      const float* __restrict__ bg2, const float* __restrict__ dinv,
                      float* __restrict__ xw2, float* __restrict__ h2)
{
    int t = blockIdx.x * 256 + threadIdx.x;
    int i = t >> 6, g = t & 63;
    float s = 0.0f;
    for (int f = 0; f < kGH; ++f)
        s = fmaf(fmaxf(h1[i * kGH + f], 0.0f), Wg2[f * kGH + g], s);
    xw2[t] = s;
    float di = dinv[i];
    h2[t] = bg2[g] + di * di * s;
}

__global__ void k_head(const float* __restrict__ h2, const float* __restrict__ Wl,
                       const float* __restrict__ bl, float* __restrict__ out)
{
    int b = blockIdx.x;
    int t = threadIdx.x;           // 256
    int g = t & 63, part = t >> 6; // 4 parts
    float s = 0.0f;
    for (int r = part; r < kR; r += 4)
        s += h2[(size_t)(b * kR + r) * kGH + g];
    __shared__ float red[4][64];
    __shared__ float pooled[64];
    __shared__ float lg[kNCLS];
    red[part][g] = s;
    __syncthreads();
    if (t < 64) pooled[t] = (red[0][t] + red[1][t] + red[2][t] + red[3][t]) * (1.0f / kR);
    __syncthreads();
    if (t < kNCLS) {
        float s2 = bl[t];
        for (int gg = 0; gg < kGH; ++gg) s2 = fmaf(pooled[gg], Wl[gg * kNCLS + t], s2);
        lg[t] = s2;
    }
    __syncthreads();
    if (t == 0) {
        float mx = lg[0];
        for (int j = 1; j < kNCLS; ++j) mx = fmaxf(mx, lg[j]);
        float ssum = 0.0f, ex[kNCLS];
        for (int j = 0; j < kNCLS; ++j) { ex[j] = expf(lg[j] - mx); ssum += ex[j]; }
        for (int j = 0; j < kNCLS; ++j) out[b * kNCLS + j] = ex[j] / ssum;
    }
}

extern "C" void kernel_launch(void* const* d_in, const int* in_sizes, int n_in,
                              void* d_out, int out_size, void* d_ws, size_t ws_size,
                              hipStream_t stream)
{
    const float* x      = (const float*)d_in[0];
    const int*   ei     = (const int*)d_in[1];
    // d_in[2] = batch_vec (unused; derivable as i / kR)
    const int*   idx    = (const int*)d_in[3];
    const float* Wconv  = (const float*)d_in[4];
    const float* bconv  = (const float*)d_in[5];
    const float* Wdec   = (const float*)d_in[6];
    const float* bdec   = (const float*)d_in[7];
    const float* edge_w = (const float*)d_in[8];
    const float* Wg1    = (const float*)d_in[9];
    const float* bg1    = (const float*)d_in[10];
    const float* Wg2    = (const float*)d_in[11];
    const float* bg2    = (const float*)d_in[12];
    const float* Wl     = (const float*)d_in[13];
    const float* bl     = (const float*)d_in[14];

    float* ws   = (float*)d_ws;
    float* emb  = ws + OFF_EMB;
    float* deg  = ws + OFF_DEG;
    float* dinv = ws + OFF_DINV;
    float* norm = ws + OFF_NORM;
    float* xw   = ws + OFF_XW;    // xw1 then xw2 (aliased)
    float* h1   = ws + OFF_H1;
    float* h2   = ws + OFF_H2;

    hipMemsetAsync(emb, 0, (size_t)kN * kENC * sizeof(float), stream);
    hipMemsetAsync(deg, 0, (size_t)kN * sizeof(float), stream);

    k_conv_emb<<<kR * 2, 320, 0, stream>>>(x, idx, Wconv, bconv, Wdec, emb);

    k_deg <<<(kE + 255) / 256, 256, 0, stream>>>(ei, edge_w, deg);
    k_dinv<<<(kN + 255) / 256, 256, 0, stream>>>(deg, dinv);
    k_norm<<<(kE + 255) / 256, 256, 0, stream>>>(ei, edge_w, dinv, norm);

    k_xw1<<<kN * kGH / 256, 256, 0, stream>>>(emb, bdec, Wg1, bg1, dinv, xw, h1);
    k_scatter<<<kE * kGH / 256, 256, 0, stream>>>(ei, norm, xw, h1);
    k_xw2<<<kN * kGH / 256, 256, 0, stream>>>(h1, Wg2, bg2, dinv, xw, h2);
    k_scatter<<<kE * kGH / 256, 256, 0, stream>>>(ei, norm, xw, h2);

    k_head<<<kB, 256, 0, stream>>>(h2, Wl, bl, (float*)d_out);
}